// Round 1
// baseline (286.829 us; speedup 1.0000x reference)
//
#include <hip/hip_runtime.h>
#include <hip/hip_bf16.h>

// MHA: x[4,2048,1024] fp32, 16 heads x 64, no 1/sqrt(d) scale.
// R9: gemm_qkv ported to the 256^2 / BK=64 / 8-wave / 8-phase counted-vmcnt
// schedule (T2 XOR-swizzle both-sides + T4 vmcnt(4)@ph4,8 + T5 setprio).
// 128 KiB LDS double buffer; stage plan ph1/2=A(T+1), ph3/4=B(T+2),
// ph5/6=A(T+2), ph7/8=B(T+3); V-blocks store transposed direct-to-global
// (8B packed along 4 consecutive rows). attn (90us) / proj / cvt unchanged.

typedef short short8 __attribute__((ext_vector_type(8)));
typedef float float4v __attribute__((ext_vector_type(4)));

#define MFMA16(a, b, c) __builtin_amdgcn_mfma_f32_16x16x32_bf16((a), (b), (c), 0, 0, 0)
#define LOG2E 1.4426950408889634f

#define B_SZ 4
#define T_SZ 2048
#define D_SZ 1024
#define NH 16
#define HD 64
#define M_SZ (B_SZ * T_SZ)  // 8192

__device__ __forceinline__ unsigned short f2bf(float f) {
  unsigned int u = __float_as_uint(f);
  u += 0x7fffu + ((u >> 16) & 1u);
  return (unsigned short)(u >> 16);
}

__device__ __forceinline__ float fexp2(float x) {
#if __has_builtin(__builtin_amdgcn_exp2f)
  return __builtin_amdgcn_exp2f(x);  // bare v_exp_f32
#else
  return exp2f(x);
#endif
}

__device__ __forceinline__ void gl_lds16(const unsigned short* g, unsigned short* l) {
  __builtin_amdgcn_global_load_lds(
      (const __attribute__((address_space(1))) unsigned int*)g,
      (__attribute__((address_space(3))) unsigned int*)l, 16, 0, 0);
}

// ---------------- fp32 -> bf16 converts ----------------
__global__ __launch_bounds__(256) void cvt_kernel(const float* __restrict__ in,
                                                  unsigned short* __restrict__ out,
                                                  float scale, long n) {
  long i = ((long)blockIdx.x * 256 + threadIdx.x) * 4;
  if (i >= n) return;
  float4 v = *(const float4*)(in + i);
  uint2 o;
  o.x = (unsigned)f2bf(v.x * scale) | ((unsigned)f2bf(v.y * scale) << 16);
  o.y = (unsigned)f2bf(v.z * scale) | ((unsigned)f2bf(v.w * scale) << 16);
  *(uint2*)(out + i) = o;
}

__global__ __launch_bounds__(256) void cvt_w(const float* __restrict__ w0,
                                             const float* __restrict__ w1,
                                             const float* __restrict__ w2,
                                             const float* __restrict__ w3,
                                             unsigned short* __restrict__ out, long per) {
  long i = ((long)blockIdx.x * 256 + threadIdx.x) * 4;
  int which = (int)(i / per);
  const float* src = which == 0 ? w0 : which == 1 ? w1 : which == 2 ? w2 : w3;
  float scale = which == 0 ? LOG2E : 1.0f;
  long j = i - (long)which * per;
  float4 v = *(const float4*)(src + j);
  uint2 o;
  o.x = (unsigned)f2bf(v.x * scale) | ((unsigned)f2bf(v.y * scale) << 16);
  o.y = (unsigned)f2bf(v.z * scale) | ((unsigned)f2bf(v.w * scale) << 16);
  *(uint2*)(out + i) = o;
}

__global__ __launch_bounds__(256) void cvt_bias(const float* __restrict__ b0,
                                                const float* __restrict__ b1,
                                                const float* __restrict__ b2,
                                                float* __restrict__ out) {
  int i = blockIdx.x * 256 + threadIdx.x;  // 0..3071
  float v;
  if (i < 1024) v = b0[i] * LOG2E;
  else if (i < 2048) v = b1[i - 1024];
  else v = b2[i - 2048];
  out[i] = v;
}

// ---------------- 8-phase 256^2 GEMM helpers ----------------
// LDS tile layout: [256 rows][8 chunks of 8 shorts], chunk c holds source
// chunk c ^ (row&7) (staged via pre-swizzled global source; gl_lds dest is
// linear). Read of source col g at row r: chunk (g/8) ^ (r&7). Conflict-free
// b128 reads within each 8-lane group (same pattern as attn_kernel).
__device__ __forceinline__ short8 ldf(const unsigned short* b, int row, int col) {
  return *(const short8*)(b + row * 64 + (col ^ ((row & 7) * 8)));
}

__device__ __forceinline__ void ld_a(const unsigned short* bA, int rbase, int ln, int q,
                                     short8 f[4][2]) {
#pragma unroll
  for (int m = 0; m < 4; ++m)
#pragma unroll
    for (int ks = 0; ks < 2; ++ks)
      f[m][ks] = ldf(bA, rbase + m * 16 + ln, ks * 32 + q * 8);
}

__device__ __forceinline__ void ld_b(const unsigned short* bB, int rbase, int ln, int q,
                                     short8 f[2][2]) {
#pragma unroll
  for (int n = 0; n < 2; ++n)
#pragma unroll
    for (int ks = 0; ks < 2; ++ks)
      f[n][ks] = ldf(bB, rbase + n * 16 + ln, ks * 32 + q * 8);
}

__device__ __forceinline__ void mf_q(float4v (&acc)[8][4], const short8 af[4][2],
                                     const short8 bf[2][2], int mo, int no) {
#pragma unroll
  for (int m = 0; m < 4; ++m)
#pragma unroll
    for (int n = 0; n < 2; ++n) {
      float4v c = acc[m + mo][n + no];
      c = MFMA16(af[m][0], bf[n][0], c);
      c = MFMA16(af[m][1], bf[n][1], c);
      acc[m + mo][n + no] = c;
    }
}

// stage one 128x64 half-tile (rows row0..row0+127, k-cols kcol..kcol+63) into
// dst (linear [128][64] shorts). Source col pre-swizzled: (l7^l3)*8.
__device__ __forceinline__ void stg_half(const unsigned short* __restrict__ g, long row0,
                                         int kcol, unsigned short* dst, int wave, int l3,
                                         int l7) {
  const int cs = (l7 ^ l3) * 8;
#pragma unroll
  for (int c = 0; c < 2; ++c)
    gl_lds16(g + (row0 + c * 64 + wave * 8 + l3) * (long)D_SZ + kcol + cs,
             dst + c * 4096 + wave * 512);
}

#define PH_PRE                                            \
  do {                                                    \
    __builtin_amdgcn_s_barrier();                         \
    asm volatile("s_waitcnt lgkmcnt(0)" ::: "memory");    \
    __builtin_amdgcn_s_setprio(1);                        \
  } while (0)
#define PH_POST                                           \
  do {                                                    \
    __builtin_amdgcn_s_setprio(0);                        \
    __builtin_amdgcn_s_barrier();                         \
  } while (0)

// ---------------- fused QKV gemm: C[8192,3072] = x . [Wq;Wk;Wv]^T + b ----------------
// 256x256 tile, BK=64, 512 threads (8 waves 2Mx4N, 128x64 each), 8-phase.
__global__ __launch_bounds__(512, 2) void gemm_qkv(const unsigned short* __restrict__ A,
                                                   const unsigned short* __restrict__ W,
                                                   const float* __restrict__ bias,
                                                   unsigned short* __restrict__ Qb,
                                                   unsigned short* __restrict__ Kb,
                                                   unsigned short* __restrict__ Vt) {
  __shared__ __align__(16) unsigned short sm[65536];  // 128 KiB
  unsigned short* sA0 = sm;            // buf0 A [256][64]
  unsigned short* sB0 = sm + 16384;    // buf0 B
  unsigned short* sA1 = sm + 32768;    // buf1 A
  unsigned short* sB1 = sm + 49152;    // buf1 B
  const int tid = threadIdx.x;
  const int wave = tid >> 6, lane = tid & 63;
  const int q = lane >> 4, ln = lane & 15;
  const int l7 = lane & 7, l3 = lane >> 3;
  const int wm = (wave >> 2) * 128, wn = (wave & 3) * 64;
  const long m0 = (long)blockIdx.y * 256;
  const long n0 = (long)blockIdx.x * 256;

  float4v acc[8][4] = {};
  short8 aL[4][2], aH[4][2], bL[2][2], bH[2][2];

  // prologue: A(0) h0/h1, B(0) h0/h1, B(1) h0/h1  (A(1) staged at ph1/2)
  stg_half(A, m0, 0, sA0, wave, l3, l7);
  stg_half(A, m0 + 128, 0, sA0 + 8192, wave, l3, l7);
  stg_half(W, n0, 0, sB0, wave, l3, l7);
  stg_half(W, n0 + 128, 0, sB0 + 8192, wave, l3, l7);
  stg_half(W, n0, 64, sB1, wave, l3, l7);
  stg_half(W, n0 + 128, 64, sB1 + 8192, wave, l3, l7);
  __syncthreads();  // one-time full drain

#pragma unroll 1
  for (int it = 0; it < 8; ++it) {
    const int T = it * 2;
    const int k1 = (T + 1) * 64;
    const int k2 = (T + 2 < 16 ? T + 2 : 15) * 64;  // clamp: last-iter stages
    const int k3 = (T + 3 < 16 ? T + 3 : 15) * 64;  // land in consumed regions

    // ---- K-tile T (buf0) ----
    // ph1: Q0 (aLo x bLo); stage A(T+1) h0
    ld_a(sA0, wm, ln, q, aL);
    ld_b(sB0, wn, ln, q, bL);
    stg_half(A, m0, k1, sA1, wave, l3, l7);
    PH_PRE; mf_q(acc, aL, bL, 0, 0); PH_POST;
    // ph2: Q1 (aLo x bHi); stage A(T+1) h1   [B(T) fully read after this ph]
    ld_b(sB0, wn + 32, ln, q, bH);
    stg_half(A, m0 + 128, k1, sA1 + 8192, wave, l3, l7);
    PH_PRE; mf_q(acc, aL, bH, 0, 2); PH_POST;
    // ph3: Q2 (aHi x bLo); stage B(T+2) h0   [A(T) fully read after this ph]
    ld_a(sA0, wm + 64, ln, q, aH);
    stg_half(W, n0, k2, sB0, wave, l3, l7);
    PH_PRE; mf_q(acc, aH, bL, 4, 0); PH_POST;
    // ph4: Q3 (aHi x bHi); stage B(T+2) h1; counted wait -> A(T+1)/B(T+1) landed
    stg_half(W, n0 + 128, k2, sB0 + 8192, wave, l3, l7);
    asm volatile("s_waitcnt vmcnt(4)" ::: "memory");
    PH_PRE; mf_q(acc, aH, bH, 4, 2); PH_POST;

    // ---- K-tile T+1 (buf1) ----
    // ph5: Q0; stage A(T+2) h0
    ld_a(sA1, wm, ln, q, aL);
    ld_b(sB1, wn, ln, q, bL);
    stg_half(A, m0, k2, sA0, wave, l3, l7);
    PH_PRE; mf_q(acc, aL, bL, 0, 0); PH_POST;
    // ph6: Q1; stage A(T+2) h1
    ld_b(sB1, wn + 32, ln, q, bH);
    stg_half(A, m0 + 128, k2, sA0 + 8192, wave, l3, l7);
    PH_PRE; mf_q(acc, aL, bH, 0, 2); PH_POST;
    // ph7: Q2; stage B(T+3) h0
    ld_a(sA1, wm + 64, ln, q, aH);
    stg_half(W, n0, k3, sB1, wave, l3, l7);
    PH_PRE; mf_q(acc, aH, bL, 4, 0); PH_POST;
    // ph8: Q3; stage B(T+3) h1; counted wait -> A(T+2)/B(T+2) landed
    stg_half(W, n0 + 128, k3, sB1 + 8192, wave, l3, l7);
    asm volatile("s_waitcnt vmcnt(4)" ::: "memory");
    PH_PRE; mf_q(acc, aH, bH, 4, 2); PH_POST;
  }
  // drain in-flight LDS-DMA before wavegroup can retire (LDS dealloc safety)
  asm volatile("s_waitcnt vmcnt(0)" ::: "memory");

  if ((int)n0 < 2048) {
    unsigned short* dst = (int)n0 < 1024 ? Qb : Kb;
    const int coff = (int)n0 < 1024 ? 0 : 1024;
#pragma unroll
    for (int i = 0; i < 8; ++i) {
      long rowb = m0 + wm + i * 16 + q * 4;
#pragma unroll
      for (int j = 0; j < 4; ++j) {
        long col = n0 + wn + j * 16 + ln;
        float bv = bias[col];
#pragma unroll
        for (int r = 0; r < 4; ++r)
          dst[(rowb + r) * (long)D_SZ + col - coff] = f2bf(acc[i][j][r] + bv);
      }
    }
  } else {
    // V: direct transposed store; 4 consecutive rows (q*4+r) pack into 8B
#pragma unroll
    for (int i = 0; i < 8; ++i) {
      long rowb = m0 + wm + i * 16 + q * 4;
#pragma unroll
      for (int j = 0; j < 4; ++j) {
        int cl = wn + j * 16 + ln;
        float bv = bias[n0 + cl];
        unsigned p01 = (unsigned)f2bf(acc[i][j][0] + bv) |
                       ((unsigned)f2bf(acc[i][j][1] + bv) << 16);
        unsigned p23 = (unsigned)f2bf(acc[i][j][2] + bv) |
                       ((unsigned)f2bf(acc[i][j][3] + bv) << 16);
        uint2 wv;
        wv.x = p01;
        wv.y = p23;
        *(uint2*)(Vt + ((long)(n0 - 2048) + cl) * (long)M_SZ + rowb) = wv;
      }
    }
  }
}

// ---------------- proj gemm: out[8192,1024] = Ob . Wp^T + bp (fp32) ----------------
__global__ __launch_bounds__(256, 3) void gemm_proj(const unsigned short* __restrict__ A,
                                                    const unsigned short* __restrict__ W,
                                                    const float* __restrict__ bias,
                                                    float* __restrict__ Cf) {
  __shared__ __align__(16) unsigned short As[128 * 64];
  __shared__ __align__(16) unsigned short Bs[128 * 64];
  const int tid = threadIdx.x;
  const int wave = tid >> 6, lane = tid & 63;
  const int q = lane >> 4, ln = lane & 15;
  const int wm = (wave >> 1) * 64, wn = (wave & 1) * 64;
  const long m0 = (long)blockIdx.y * 128;
  const long n0 = (long)blockIdx.x * 128;
  const int srow = lane >> 3, scol = (lane & 7) * 8;
  const int K = D_SZ;

  float4v acc[4][4] = {};
  for (int k0 = 0; k0 < K; k0 += 64) {
    for (int t = 0; t < 4; ++t) {
      int seg = wave * 4 + t;
      int row = seg * 8 + srow;
      gl_lds16(A + (m0 + row) * (long)K + k0 + scol, As + seg * 512);
      gl_lds16(W + (n0 + row) * (long)K + k0 + scol, Bs + seg * 512);
    }
    __syncthreads();
    for (int ks = 0; ks < 2; ++ks) {
      short8 af[4], bf[4];
      for (int i = 0; i < 4; ++i)
        af[i] = *(const short8*)(As + (wm + i * 16 + ln) * 64 + ks * 32 + q * 8);
      for (int j = 0; j < 4; ++j)
        bf[j] = *(const short8*)(Bs + (wn + j * 16 + ln) * 64 + ks * 32 + q * 8);
      for (int i = 0; i < 4; ++i)
        for (int j = 0; j < 4; ++j)
          acc[i][j] = MFMA16(af[i], bf[j], acc[i][j]);
    }
    __syncthreads();
  }
  for (int i = 0; i < 4; ++i) {
    long rowb = m0 + wm + i * 16 + q * 4;
    for (int j = 0; j < 4; ++j) {
      long col = n0 + wn + j * 16 + ln;
      float bv = bias[col];
      for (int r = 0; r < 4; ++r)
        Cf[(rowb + r) * (long)D_SZ + col] = acc[i][j][r] + bv;
    }
  }
}

// ---------------- flash attention (unchanged: 90 us) ----------------
__global__ __launch_bounds__(512, 4) void attn_kernel(const unsigned short* __restrict__ Qb,
                                                      const unsigned short* __restrict__ Kb,
                                                      const unsigned short* __restrict__ Vt,
                                                      unsigned short* __restrict__ Ob) {
  // KV[buf][K 4096 | V 4096] shorts, swizzle: off(row,c8) = row*64 + ((c8 ^ (row&7))*8)
  __shared__ __align__(16) unsigned short KV[16384];   // 32768 B
  __shared__ __align__(16) unsigned short Pp[10240];   // 8 waves x 32 rows x pitch 40

  const int tid = threadIdx.x;
  const int wave = tid >> 6, lane = tid & 63;
  const int q = lane >> 4, ln = lane & 15;
  const int l7 = lane & 7, l3 = lane >> 3;
  const int qt = blockIdx.x, h = blockIdx.y, b = blockIdx.z;

  const long baseQ = ((long)b * T_SZ + qt * 256) * D_SZ + h * HD;
  const long baseK = (long)b * T_SZ * D_SZ + h * HD;
  const long baseV = (long)h * HD * M_SZ + (long)b * T_SZ;
  const int cs = ((l7 ^ l3) * 8);  // per-lane source column (shorts), matches swizzle

  short8 qf[2][2];
  for (int i = 0; i < 2; ++i)
    for (int ks = 0; ks < 2; ++ks)
      qf[i][ks] = *(const short8*)(Qb + baseQ + (long)(wave * 32 + i * 16 + ln) * D_SZ +
                                   ks * 32 + q * 8);

  float4v o[2][4] = {};
  float lp[2] = {};
  unsigned short* Ppw = Pp + wave * (32 * 40);
  const int swz = (ln & 7) * 8;  // frag-read swizzle term

// stage kv-tile kt_ into buffer base_: wave w stages K seg w and V seg w (1 KiB each)
#define STAGE(kt_, base_)                                                                \
  {                                                                                      \
    int row = wave * 8 + l3;                                                             \
    gl_lds16(Kb + baseK + (long)((kt_)*64 + row) * D_SZ + cs, (base_) + wave * 512);     \
    gl_lds16(Vt + baseV + (long)row * M_SZ + (kt_)*64 + cs, (base_) + 4096 + wave * 512);\
  }

  STAGE(0, KV)

  for (int kt = 0; kt < 32; ++kt) {
    unsigned short* cur = KV + (kt & 1) * 8192;
    unsigned short* nxt = KV + ((kt & 1) ^ 1) * 8192;
    __syncthreads();  // vmcnt drain: cur staged; prior readers of nxt done
    if (kt < 31) { STAGE(kt + 1, nxt) }  // async, lands during compute below

    // S^T = K Q'^T ; D: row = key (q*4+r), col = qrow (ln)
    short8 kf[4][2];
    for (int c = 0; c < 4; ++c)
      for (int ks = 0; ks < 2; ++ks)
        kf[c][ks] = *(const short8*)(cur + (c * 16 + ln) * 64 + ((ks * 32 + q * 8) ^ swz));
    float4v s[4][2];
    for (int c = 0; c < 4; ++c)
      for (int i = 0; i < 2; ++i) {
        float4v z = {};
        z = MFMA16(kf[c][0], qf[i][0], z);
        z = MFMA16(kf[c][1], qf[i][1], z);
        s[c][i] = z;
      }

    // two phases over key halves: exp2 -> Pp[qrow][key%32] -> PV MFMA
    for (int ks = 0; ks < 2; ++ks) {
      for (int i = 0; i < 2; ++i)
        for (int cl = 0; cl < 2; ++cl) {
          int c = 2 * ks + cl;
          float p0 = fexp2(s[c][i][0]);
          float p1 = fexp2(s[c][i][1]);
          float p2 = fexp2(s[c][i][2]);
          float p3 = fexp2(s[c][i][3]);
          lp[i] += (p0 + p1) + (p2 + p3);
          __hip_bfloat162 lo = __float22bfloat162_rn(make_float2(p0, p1));
          __hip_bfloat162 hi = __float22bfloat162_rn(make_float2(p2, p3));
          uint2 w;
          w.x = *(unsigned*)&lo;
          w.y = *(unsigned*)&hi;
          *(uint2*)(Ppw + (i * 16 + ln) * 40 + cl * 16 + q * 4) = w;
        }
      short8 vf[4];
      for (int j = 0; j < 4; ++j)
        vf[j] = *(const short8*)(cur + 4096 + (j * 16 + ln) * 64 + ((ks * 32 + q * 8) ^ swz));
      short8 pf[2];
      for (int i = 0; i < 2; ++i)
        pf[i] = *(const short8*)(Ppw + (i * 16 + ln) * 40 + q * 8);
      for (int i = 0; i < 2; ++i)
        for (int j = 0; j < 4; ++j)
          o[i][j] = MFMA16(pf[i], vf[j], o[i][j]);
    }
  }

  for (int i = 0; i < 2; ++i) {
    float l = lp[i];
    l += __shfl_xor(l, 16, 64);
    l += __shfl_xor(l, 32, 64);
    float inv = 1.f / l;  // lane holds qrow = i*16+ln
    for (int r = 0; r < 4; ++r) {
      int src = (lane & 48) | (q * 4 + r);
      float invr = __shfl(inv, src, 64);
      int row = qt * 256 + wave * 32 + i * 16 + q * 4 + r;
      long base = ((long)b * T_SZ + row) * D_SZ + h * HD;
      for (int j = 0; j < 4; ++j)
        Ob[base + j * 16 + ln] = f2bf(o[i][j][r] * invr);
    }
  }
#undef STAGE
}

extern "C" void kernel_launch(void* const* d_in, const int* in_sizes, int n_in,
                              void* d_out, int out_size, void* d_ws, size_t ws_size,
                              hipStream_t stream) {
  const float* x = (const float*)d_in[0];
  const float* Wq = (const float*)d_in[1];
  const float* bq = (const float*)d_in[2];
  const float* Wk = (const float*)d_in[3];
  const float* bk = (const float*)d_in[4];
  const float* Wv = (const float*)d_in[5];
  const float* bv = (const float*)d_in[6];
  const float* Wp = (const float*)d_in[7];
  const float* bp = (const float*)d_in[8];
  float* out = (float*)d_out;

  const long MX = (long)M_SZ * D_SZ;
  const long MW = (long)D_SZ * D_SZ;
  unsigned short* ws = (unsigned short*)d_ws;
  unsigned short* xb = ws;
  unsigned short* Wcat = xb + MX;
  float* bcat = (float*)(Wcat + 4 * MW);
  unsigned short* Qb = (unsigned short*)(bcat + 3072);
  unsigned short* Kb = Qb + MX;
  unsigned short* Vtb = Kb + MX;
  unsigned short* Ob = Vtb + MX;

  cvt_kernel<<<(int)(MX / 1024), 256, 0, stream>>>(x, xb, 1.0f, MX);
  cvt_w<<<(int)(4 * MW / 1024), 256, 0, stream>>>(Wq, Wk, Wv, Wp, Wcat, MW);
  cvt_bias<<<12, 256, 0, stream>>>(bq, bk, bv, bcat);

  dim3 gq(3072 / 256, M_SZ / 256);  // (12, 32) = 384 blocks x 512 threads
  gemm_qkv<<<gq, 512, 0, stream>>>(xb, Wcat, bcat, Qb, Kb, Vtb);

  dim3 ag(T_SZ / 256, NH, B_SZ);  // (8, 16, 4) = 512 blocks of 512 threads
  attn_kernel<<<ag, 512, 0, stream>>>(Qb, Kb, Vtb, Ob);

  dim3 gp(D_SZ / 128, M_SZ / 128);  // (8, 64)
  gemm_proj<<<gp, 256, 0, stream>>>(Ob, Wcat + 3 * MW, bp, out);
}

// Round 2
// 282.654 us; speedup vs baseline: 1.0148x; 1.0148x over previous
//
#include <hip/hip_runtime.h>
#include <hip/hip_bf16.h>

// MHA: x[4,2048,1024] fp32, 16 heads x 64, no 1/sqrt(d) scale.
// R10: revert gemm_qkv to R8 128^2 (8-phase port was neutral at K=1024 /
// 1-block-per-CU: fill+tail ate the pipeline gain). attn: q-tile 256->128
// (grid 512->1024 blocks; Pp 20K->10K; LDS 43KB -> 3 blocks/CU, 24 waves/CU
// vs grid-limited 2/16 before) + s_setprio(1) around MFMA clusters (m191:
// +4-7% attn). cvt kernels fused into one launch (fewer gaps).

typedef short short8 __attribute__((ext_vector_type(8)));
typedef float float4v __attribute__((ext_vector_type(4)));

#define MFMA16(a, b, c) __builtin_amdgcn_mfma_f32_16x16x32_bf16((a), (b), (c), 0, 0, 0)
#define LOG2E 1.4426950408889634f

#define B_SZ 4
#define T_SZ 2048
#define D_SZ 1024
#define NH 16
#define HD 64
#define M_SZ (B_SZ * T_SZ)  // 8192
#define MW_SZ (D_SZ * D_SZ) // 1048576

__device__ __forceinline__ unsigned short f2bf(float f) {
  unsigned int u = __float_as_uint(f);
  u += 0x7fffu + ((u >> 16) & 1u);
  return (unsigned short)(u >> 16);
}

__device__ __forceinline__ float fexp2(float x) {
#if __has_builtin(__builtin_amdgcn_exp2f)
  return __builtin_amdgcn_exp2f(x);  // bare v_exp_f32
#else
  return exp2f(x);
#endif
}

__device__ __forceinline__ void gl_lds16(const unsigned short* g, unsigned short* l) {
  __builtin_amdgcn_global_load_lds(
      (const __attribute__((address_space(1))) unsigned int*)g,
      (__attribute__((address_space(3))) unsigned int*)l, 16, 0, 0);
}

// ---------------- fused fp32 -> bf16 converts (one launch) ----------------
// blocks [0,8192): x -> xb ; [8192,12288): Wq|Wk|Wv|Wp -> Wcat (Wq*log2e) ;
// [12288,12291): bias concat (bq*log2e | bk | bv) -> bcat fp32
__global__ __launch_bounds__(256) void cvt_all(const float* __restrict__ x,
                                               const float* __restrict__ w0,
                                               const float* __restrict__ w1,
                                               const float* __restrict__ w2,
                                               const float* __restrict__ w3,
                                               const float* __restrict__ b0,
                                               const float* __restrict__ b1,
                                               const float* __restrict__ b2,
                                               unsigned short* __restrict__ xb,
                                               unsigned short* __restrict__ wout,
                                               float* __restrict__ bout) {
  const long blk = blockIdx.x;
  if (blk < 8192) {
    long i = (blk * 256 + threadIdx.x) * 4;
    float4 v = *(const float4*)(x + i);
    uint2 o;
    o.x = (unsigned)f2bf(v.x) | ((unsigned)f2bf(v.y) << 16);
    o.y = (unsigned)f2bf(v.z) | ((unsigned)f2bf(v.w) << 16);
    *(uint2*)(xb + i) = o;
  } else if (blk < 12288) {
    long i = ((blk - 8192) * 256 + threadIdx.x) * 4;  // 0 .. 4*MW
    int which = (int)(i >> 20);
    const float* src = which == 0 ? w0 : which == 1 ? w1 : which == 2 ? w2 : w3;
    float scale = which == 0 ? LOG2E : 1.0f;
    long j = i - (long)which * MW_SZ;
    float4 v = *(const float4*)(src + j);
    uint2 o;
    o.x = (unsigned)f2bf(v.x * scale) | ((unsigned)f2bf(v.y * scale) << 16);
    o.y = (unsigned)f2bf(v.z * scale) | ((unsigned)f2bf(v.w * scale) << 16);
    *(uint2*)(wout + i) = o;
  } else {
    int i = (int)((blk - 12288) * 256 + threadIdx.x) * 4;  // 0..3071, 4-aligned
    float4 v;
    if (i < 1024) {
      v = *(const float4*)(b0 + i);
      v.x *= LOG2E; v.y *= LOG2E; v.z *= LOG2E; v.w *= LOG2E;
    } else if (i < 2048) {
      v = *(const float4*)(b1 + (i - 1024));
    } else {
      v = *(const float4*)(b2 + (i - 2048));
    }
    *(float4*)(bout + i) = v;
  }
}

// ---------------- fused QKV gemm: C[8192,3072] = x . [Wq;Wk;Wv]^T + b ----------------
__global__ __launch_bounds__(256, 3) void gemm_qkv(const unsigned short* __restrict__ A,
                                                   const unsigned short* __restrict__ W,
                                                   const float* __restrict__ bias,
                                                   unsigned short* __restrict__ Qb,
                                                   unsigned short* __restrict__ Kb,
                                                   unsigned short* __restrict__ Vt) {
  __shared__ __align__(16) unsigned short smem[17408];  // As|Bs / Ct (128x136)
  unsigned short* As = smem;
  unsigned short* Bs = smem + 8192;
  unsigned short* Ct = smem;
  const int tid = threadIdx.x;
  const int wave = tid >> 6, lane = tid & 63;
  const int q = lane >> 4, ln = lane & 15;
  const int wm = (wave >> 1) * 64, wn = (wave & 1) * 64;
  const long m0 = (long)blockIdx.y * 128;
  const long n0 = (long)blockIdx.x * 128;
  const int srow = lane >> 3, scol = (lane & 7) * 8;
  const int K = D_SZ;

  float4v acc[4][4] = {};

  for (int k0 = 0; k0 < K; k0 += 64) {
    for (int t = 0; t < 4; ++t) {
      int seg = wave * 4 + t;
      int row = seg * 8 + srow;
      gl_lds16(A + (m0 + row) * (long)K + k0 + scol, As + seg * 512);
      gl_lds16(W + (n0 + row) * (long)K + k0 + scol, Bs + seg * 512);
    }
    __syncthreads();
    for (int ks = 0; ks < 2; ++ks) {
      short8 af[4], bf[4];
      for (int i = 0; i < 4; ++i)
        af[i] = *(const short8*)(As + (wm + i * 16 + ln) * 64 + ks * 32 + q * 8);
      for (int j = 0; j < 4; ++j)
        bf[j] = *(const short8*)(Bs + (wn + j * 16 + ln) * 64 + ks * 32 + q * 8);
      for (int i = 0; i < 4; ++i)
        for (int j = 0; j < 4; ++j)
          acc[i][j] = MFMA16(af[i], bf[j], acc[i][j]);
    }
    __syncthreads();
  }

  if ((int)n0 < 2048) {
    unsigned short* dst = (int)n0 < 1024 ? Qb : Kb;
    int coff = (int)n0 < 1024 ? 0 : 1024;
    for (int i = 0; i < 4; ++i) {
      long rowb = m0 + wm + i * 16 + q * 4;
      for (int j = 0; j < 4; ++j) {
        long col = n0 + wn + j * 16 + ln;
        float bv = bias[col];
        for (int r = 0; r < 4; ++r)
          dst[(rowb + r) * (long)D_SZ + col - coff] = f2bf(acc[i][j][r] + bv);
      }
    }
  } else {
    for (int i = 0; i < 4; ++i)
      for (int j = 0; j < 4; ++j) {
        int col_l = wn + j * 16 + ln;
        float bv = bias[n0 + col_l];
        __hip_bfloat162 lo =
            __float22bfloat162_rn(make_float2(acc[i][j][0] + bv, acc[i][j][1] + bv));
        __hip_bfloat162 hi =
            __float22bfloat162_rn(make_float2(acc[i][j][2] + bv, acc[i][j][3] + bv));
        uint2 w;
        w.x = *(unsigned*)&lo;
        w.y = *(unsigned*)&hi;
        *(uint2*)(Ct + col_l * 136 + wm + i * 16 + q * 4) = w;
      }
    __syncthreads();
    for (int it = 0; it < 8; ++it) {
      int idx = tid + it * 256;
      int c = idx >> 4, rb = idx & 15;
      uint4 v = *(const uint4*)(Ct + c * 136 + rb * 8);
      *(uint4*)(Vt + (n0 - 2048 + c) * (long)M_SZ + m0 + rb * 8) = v;
    }
  }
}

// ---------------- proj gemm: out[8192,1024] = Ob . Wp^T + bp (fp32) ----------------
__global__ __launch_bounds__(256, 3) void gemm_proj(const unsigned short* __restrict__ A,
                                                    const unsigned short* __restrict__ W,
                                                    const float* __restrict__ bias,
                                                    float* __restrict__ Cf) {
  __shared__ __align__(16) unsigned short As[128 * 64];
  __shared__ __align__(16) unsigned short Bs[128 * 64];
  const int tid = threadIdx.x;
  const int wave = tid >> 6, lane = tid & 63;
  const int q = lane >> 4, ln = lane & 15;
  const int wm = (wave >> 1) * 64, wn = (wave & 1) * 64;
  const long m0 = (long)blockIdx.y * 128;
  const long n0 = (long)blockIdx.x * 128;
  const int srow = lane >> 3, scol = (lane & 7) * 8;
  const int K = D_SZ;

  float4v acc[4][4] = {};
  for (int k0 = 0; k0 < K; k0 += 64) {
    for (int t = 0; t < 4; ++t) {
      int seg = wave * 4 + t;
      int row = seg * 8 + srow;
      gl_lds16(A + (m0 + row) * (long)K + k0 + scol, As + seg * 512);
      gl_lds16(W + (n0 + row) * (long)K + k0 + scol, Bs + seg * 512);
    }
    __syncthreads();
    for (int ks = 0; ks < 2; ++ks) {
      short8 af[4], bf[4];
      for (int i = 0; i < 4; ++i)
        af[i] = *(const short8*)(As + (wm + i * 16 + ln) * 64 + ks * 32 + q * 8);
      for (int j = 0; j < 4; ++j)
        bf[j] = *(const short8*)(Bs + (wn + j * 16 + ln) * 64 + ks * 32 + q * 8);
      for (int i = 0; i < 4; ++i)
        for (int j = 0; j < 4; ++j)
          acc[i][j] = MFMA16(af[i], bf[j], acc[i][j]);
    }
    __syncthreads();
  }
  for (int i = 0; i < 4; ++i) {
    long rowb = m0 + wm + i * 16 + q * 4;
    for (int j = 0; j < 4; ++j) {
      long col = n0 + wn + j * 16 + ln;
      float bv = bias[col];
      for (int r = 0; r < 4; ++r)
        Cf[(rowb + r) * (long)D_SZ + col] = acc[i][j][r] + bv;
    }
  }
}

// ---------------- flash attention: q-tile 128, 8 waves x 16 rows ----------------
// grid (16,16,4) = 1024 blocks; LDS 43008 B -> 3 blocks/CU (was grid-limited
// 2/CU at q-tile 256). setprio(1) wraps MFMA clusters (T5, m191).
__global__ __launch_bounds__(512, 4) void attn_kernel(const unsigned short* __restrict__ Qb,
                                                      const unsigned short* __restrict__ Kb,
                                                      const unsigned short* __restrict__ Vt,
                                                      unsigned short* __restrict__ Ob) {
  // KV[buf][K 4096 | V 4096] shorts, swizzle: off(row,c8) = row*64 + ((c8 ^ (row&7))*8)
  __shared__ __align__(16) unsigned short KV[16384];  // 32768 B
  __shared__ __align__(16) unsigned short Pp[5120];   // 8 waves x 16 rows x pitch 40

  const int tid = threadIdx.x;
  const int wave = tid >> 6, lane = tid & 63;
  const int q = lane >> 4, ln = lane & 15;
  const int l7 = lane & 7, l3 = lane >> 3;
  const int qt = blockIdx.x, h = blockIdx.y, b = blockIdx.z;

  const long baseQ = ((long)b * T_SZ + qt * 128) * D_SZ + h * HD;
  const long baseK = (long)b * T_SZ * D_SZ + h * HD;
  const long baseV = (long)h * HD * M_SZ + (long)b * T_SZ;
  const int cs = ((l7 ^ l3) * 8);  // per-lane source column (shorts), matches swizzle

  short8 qf[2];
  for (int ks = 0; ks < 2; ++ks)
    qf[ks] = *(const short8*)(Qb + baseQ + (long)(wave * 16 + ln) * D_SZ + ks * 32 + q * 8);

  float4v o[4] = {};
  float lp = 0.f;
  unsigned short* Ppw = Pp + wave * (16 * 40);
  const int swz = (ln & 7) * 8;  // frag-read swizzle term

// stage kv-tile kt_ into buffer base_: wave w stages K seg w and V seg w (1 KiB each)
#define STAGE(kt_, base_)                                                                \
  {                                                                                      \
    int row = wave * 8 + l3;                                                             \
    gl_lds16(Kb + baseK + (long)((kt_)*64 + row) * D_SZ + cs, (base_) + wave * 512);     \
    gl_lds16(Vt + baseV + (long)row * M_SZ + (kt_)*64 + cs, (base_) + 4096 + wave * 512);\
  }

  STAGE(0, KV)

  for (int kt = 0; kt < 32; ++kt) {
    unsigned short* cur = KV + (kt & 1) * 8192;
    unsigned short* nxt = KV + ((kt & 1) ^ 1) * 8192;
    __syncthreads();  // vmcnt drain: cur staged; prior readers of nxt done
    if (kt < 31) { STAGE(kt + 1, nxt) }  // async, lands during compute below

    // S^T = K Q'^T ; D: row = key (q*4+r), col = qrow (ln)
    short8 kf[4][2];
    for (int c = 0; c < 4; ++c)
      for (int ks = 0; ks < 2; ++ks)
        kf[c][ks] = *(const short8*)(cur + (c * 16 + ln) * 64 + ((ks * 32 + q * 8) ^ swz));
    float4v s[4];
    __builtin_amdgcn_s_setprio(1);
    for (int c = 0; c < 4; ++c) {
      float4v z = {};
      z = MFMA16(kf[c][0], qf[0], z);
      z = MFMA16(kf[c][1], qf[1], z);
      s[c] = z;
    }
    __builtin_amdgcn_s_setprio(0);

    // two phases over key halves: exp2 -> Pp[qrow][key%32] -> PV MFMA
    for (int ks = 0; ks < 2; ++ks) {
      for (int cl = 0; cl < 2; ++cl) {
        int c = 2 * ks + cl;
        float p0 = fexp2(s[c][0]);
        float p1 = fexp2(s[c][1]);
        float p2 = fexp2(s[c][2]);
        float p3 = fexp2(s[c][3]);
        lp += (p0 + p1) + (p2 + p3);
        __hip_bfloat162 lo = __float22bfloat162_rn(make_float2(p0, p1));
        __hip_bfloat162 hi = __float22bfloat162_rn(make_float2(p2, p3));
        uint2 w;
        w.x = *(unsigned*)&lo;
        w.y = *(unsigned*)&hi;
        *(uint2*)(Ppw + ln * 40 + cl * 16 + q * 4) = w;
      }
      short8 vf[4];
      for (int j = 0; j < 4; ++j)
        vf[j] = *(const short8*)(cur + 4096 + (j * 16 + ln) * 64 + ((ks * 32 + q * 8) ^ swz));
      short8 pf = *(const short8*)(Ppw + ln * 40 + q * 8);
      __builtin_amdgcn_s_setprio(1);
      for (int j = 0; j < 4; ++j)
        o[j] = MFMA16(pf, vf[j], o[j]);
      __builtin_amdgcn_s_setprio(0);
    }
  }

  {
    float l = lp;
    l += __shfl_xor(l, 16, 64);
    l += __shfl_xor(l, 32, 64);
    float inv = 1.f / l;  // lane holds qrow = ln
    for (int r = 0; r < 4; ++r) {
      int src = (lane & 48) | (q * 4 + r);
      float invr = __shfl(inv, src, 64);
      int row = qt * 128 + wave * 16 + q * 4 + r;
      long base = ((long)b * T_SZ + row) * D_SZ + h * HD;
      for (int j = 0; j < 4; ++j)
        Ob[base + j * 16 + ln] = f2bf(o[j][r] * invr);
    }
  }
#undef STAGE
}

extern "C" void kernel_launch(void* const* d_in, const int* in_sizes, int n_in,
                              void* d_out, int out_size, void* d_ws, size_t ws_size,
                              hipStream_t stream) {
  const float* x = (const float*)d_in[0];
  const float* Wq = (const float*)d_in[1];
  const float* bq = (const float*)d_in[2];
  const float* Wk = (const float*)d_in[3];
  const float* bk = (const float*)d_in[4];
  const float* Wv = (const float*)d_in[5];
  const float* bv = (const float*)d_in[6];
  const float* Wp = (const float*)d_in[7];
  const float* bp = (const float*)d_in[8];
  float* out = (float*)d_out;

  const long MX = (long)M_SZ * D_SZ;
  const long MW = (long)MW_SZ;
  unsigned short* ws = (unsigned short*)d_ws;
  unsigned short* xb = ws;
  unsigned short* Wcat = xb + MX;
  float* bcat = (float*)(Wcat + 4 * MW);
  unsigned short* Qb = (unsigned short*)(bcat + 3072);
  unsigned short* Kb = Qb + MX;
  unsigned short* Vtb = Kb + MX;
  unsigned short* Ob = Vtb + MX;

  cvt_all<<<12291, 256, 0, stream>>>(x, Wq, Wk, Wv, Wp, bq, bk, bv, xb, Wcat, bcat);

  dim3 gq(3072 / 128, M_SZ / 128);  // (24, 64)
  gemm_qkv<<<gq, 256, 0, stream>>>(xb, Wcat, bcat, Qb, Kb, Vtb);

  dim3 ag(T_SZ / 128, NH, B_SZ);  // (16, 16, 4) = 1024 blocks of 512 threads
  attn_kernel<<<ag, 512, 0, stream>>>(Qb, Kb, Vtb, Ob);

  dim3 gp(D_SZ / 128, M_SZ / 128);  // (8, 64)
  gemm_proj<<<gp, 256, 0, stream>>>(Ob, Wcat + 3 * MW, bp, out);
}